// Round 2
// baseline (90.804 us; speedup 1.0000x reference)
//
#include <hip/hip_runtime.h>

#define G_   5000
#define B_   128
#define S_   32
#define NTH  256
#define GCHUNKS 20   // ceil(5000/256)

// ---------------- kernel A: zero the atomic-max cell (d_ws is poisoned 0xAA) ----
__global__ void init_max(int* wsmax) { *wsmax = 0; }  // outputs all > 0, so 0 floor ok

// ---------------- kernel B: main clause evaluation ------------------------------
// Block: 256 threads; owns 2 consecutive batch rows (blockIdx.y) and a chunk of
// 256 g's (blockIdx.x). x rows staged interleaved in LDS so one ds_read_b64
// serves both batches per gathered index.
__global__ __launch_bounds__(NTH)
void clause_main(const float* __restrict__ x,
                 const int*  __restrict__ idx,   // harness delivers indices as int32
                 float* __restrict__ out,
                 int*   __restrict__ wsmax) {
    __shared__ float xi[G_ * 2];          // 40,000 B: xi[2*i+j] = x[b0+j][i]
    __shared__ float red[NTH / 64];

    const int tid = threadIdx.x;
    const int b0  = blockIdx.y * 2;

    // ---- stage 2 x-rows, interleaved (transpose in registers) ----
    const float4* r0 = (const float4*)(x + (size_t)b0 * G_);
    const float4* r1 = (const float4*)(x + (size_t)(b0 + 1) * G_);  // 5000%4==0 -> aligned
    float4* xiv = (float4*)xi;
    for (int ii = tid; ii < G_ / 4; ii += NTH) {
        float4 a = r0[ii];
        float4 b = r1[ii];
        xiv[ii * 2]     = make_float4(a.x, b.x, a.y, b.y);
        xiv[ii * 2 + 1] = make_float4(a.z, b.z, a.w, b.w);
    }
    __syncthreads();

    const int g = blockIdx.x * NTH + tid;
    const float2* xi2 = (const float2*)xi;
    float m = 0.0f;

    if (g < G_) {
        // logsumexp with fixed shift: gamma*lse(body/gamma) = 0.15 + 0.01*ln(sum exp(100*body-15))
        // body in (0,1): term <= e^85, 32*e^85 ~ 2.6e38 < FLT_MAX; term >= e^-15 (fully normal).
        float accx = 0.0f, accy = 0.0f;
        const int4* ip = ((const int4*)idx) + (size_t)g * S_;
        #pragma unroll 4
        for (int s = 0; s < S_; ++s) {
            int4 id = ip[s];
            float2 v0 = xi2[id.x];
            float2 v1 = xi2[id.y];
            float2 v2 = xi2[id.z];
            float2 v3 = xi2[id.w];
            float bx = v0.x * v1.x * v2.x * v3.x;
            float by = v0.y * v1.y * v2.y * v3.y;
            accx += __expf(fmaf(bx, 100.0f, -15.0f));
            accy += __expf(fmaf(by, 100.0f, -15.0f));
        }
        float o0 = fmaf(0.01f, __logf(accx), 0.15f);
        float o1 = fmaf(0.01f, __logf(accy), 0.15f);
        out[(size_t)b0 * G_ + g]       = o0;
        out[(size_t)(b0 + 1) * G_ + g] = o1;
        m = fmaxf(o0, o1);
    }

    // ---- block max -> global atomic (positive floats: int-bit max == float max) ----
    #pragma unroll
    for (int off = 32; off >= 1; off >>= 1)
        m = fmaxf(m, __shfl_down(m, off));
    if ((tid & 63) == 0) red[tid >> 6] = m;
    __syncthreads();
    if (tid == 0) {
        float mm = fmaxf(fmaxf(red[0], red[1]), fmaxf(red[2], red[3]));
        atomicMax(wsmax, __float_as_int(mm));
    }
}

// ---------------- kernel C: conditional global-max normalization ----------------
__global__ void norm_out(float* __restrict__ out, const int* __restrict__ wsmax, int n4) {
    int i = blockIdx.x * blockDim.x + threadIdx.x;
    float mv = __int_as_float(*wsmax);
    float s  = (mv > 1.0f) ? (1.0f / mv) : 1.0f;
    if (i < n4) {
        float4 v = ((float4*)out)[i];
        v.x *= s; v.y *= s; v.z *= s; v.w *= s;
        ((float4*)out)[i] = v;
    }
}

// ---------------- launcher ------------------------------------------------------
extern "C" void kernel_launch(void* const* d_in, const int* in_sizes, int n_in,
                              void* d_out, int out_size, void* d_ws, size_t ws_size,
                              hipStream_t stream) {
    const float* x   = (const float*)d_in[0];
    const int*   idx = (const int*)d_in[1];   // int64 in reference -> int32 from harness
    float* out = (float*)d_out;
    int* wsmax = (int*)d_ws;

    init_max<<<1, 1, 0, stream>>>(wsmax);

    dim3 grid(GCHUNKS, B_ / 2);
    clause_main<<<grid, NTH, 0, stream>>>(x, idx, out, wsmax);

    const int n4 = (B_ * G_) / 4;             // 160,000
    norm_out<<<(n4 + NTH - 1) / NTH, NTH, 0, stream>>>(out, wsmax, n4);
}

// Round 3
// 89.197 us; speedup vs baseline: 1.0180x; 1.0180x over previous
//
#include <hip/hip_runtime.h>

#define G_   5000
#define B_   128
#define S_   32
#define NTH  512
#define GPB  500      // g's per block; 10 chunks * 500 = 5000
#define NCHUNK 10

// ---------------- main clause evaluation ---------------------------------------
// Block: 512 threads (8 waves); owns 2 consecutive batch rows (blockIdx.y) and a
// chunk of 500 g's (blockIdx.x). x rows staged interleaved in LDS so one
// ds_read_b64 serves both batches per gathered index. 40 KB LDS -> 4 blocks/CU;
// grid 640 blocks = fully co-resident single round (cap 1024).
__global__ __launch_bounds__(NTH)
void clause_main(const float* __restrict__ x,
                 const int*  __restrict__ idx,   // harness delivers int64 ref idx as int32
                 float* __restrict__ out,
                 int*   __restrict__ wsmax) {
    __shared__ float xi[G_ * 2];          // 40,000 B: xi[2*i+j] = x[b0+j][i]
    __shared__ float red[NTH / 64];

    const int tid = threadIdx.x;
    const int b0  = blockIdx.y * 2;

    // ---- stage 2 x-rows, interleaved (transpose in registers) ----
    const float4* r0 = (const float4*)(x + (size_t)b0 * G_);
    const float4* r1 = (const float4*)(x + (size_t)(b0 + 1) * G_);  // 5000%4==0 -> aligned
    float4* xiv = (float4*)xi;
    for (int ii = tid; ii < G_ / 4; ii += NTH) {
        float4 a = r0[ii];
        float4 b = r1[ii];
        xiv[ii * 2]     = make_float4(a.x, b.x, a.y, b.y);
        xiv[ii * 2 + 1] = make_float4(a.z, b.z, a.w, b.w);
    }
    __syncthreads();

    const int g = blockIdx.x * GPB + tid;
    const bool active = (tid < GPB);      // g < 5000 guaranteed when tid < 500
    const float2* xi2 = (const float2*)xi;
    float m = 0.0f;

    if (active) {
        // gamma*lse(body/gamma) = 0.15 + 0.01*ln(sum_s exp(100*body_s - 15))
        // body in (0,1): term <= e^85, 32*e^85 ~ 2.6e38 < FLT_MAX; term >= e^-15 (normal).
        float accx = 0.0f, accy = 0.0f;
        const int4* ip = ((const int4*)idx) + (size_t)g * S_;
        #pragma unroll 4
        for (int s = 0; s < S_; ++s) {
            int4 id = ip[s];
            float2 v0 = xi2[id.x];
            float2 v1 = xi2[id.y];
            float2 v2 = xi2[id.z];
            float2 v3 = xi2[id.w];
            float bx = v0.x * v1.x * v2.x * v3.x;
            float by = v0.y * v1.y * v2.y * v3.y;
            accx += __expf(fmaf(bx, 100.0f, -15.0f));
            accy += __expf(fmaf(by, 100.0f, -15.0f));
        }
        float o0 = fmaf(0.01f, __logf(accx), 0.15f);
        float o1 = fmaf(0.01f, __logf(accy), 0.15f);
        out[(size_t)b0 * G_ + g]       = o0;
        out[(size_t)(b0 + 1) * G_ + g] = o1;
        m = fmaxf(o0, o1);
    }

    // ---- block max -> global atomic (positive floats: int-bit max == float max) ----
    #pragma unroll
    for (int off = 32; off >= 1; off >>= 1)
        m = fmaxf(m, __shfl_down(m, off));
    if ((tid & 63) == 0) red[tid >> 6] = m;
    __syncthreads();
    if (tid == 0) {
        float mm = red[0];
        #pragma unroll
        for (int w = 1; w < NTH / 64; ++w) mm = fmaxf(mm, red[w]);
        atomicMax(wsmax, __float_as_int(mm));
    }
}

// ---------------- conditional global-max normalization --------------------------
__global__ void norm_out(float* __restrict__ out, const int* __restrict__ wsmax, int n4) {
    int i = blockIdx.x * blockDim.x + threadIdx.x;
    float mv = __int_as_float(*wsmax);
    float s  = (mv > 1.0f) ? (1.0f / mv) : 1.0f;
    if (i < n4) {
        float4 v = ((float4*)out)[i];
        v.x *= s; v.y *= s; v.z *= s; v.w *= s;
        ((float4*)out)[i] = v;
    }
}

// ---------------- launcher ------------------------------------------------------
extern "C" void kernel_launch(void* const* d_in, const int* in_sizes, int n_in,
                              void* d_out, int out_size, void* d_ws, size_t ws_size,
                              hipStream_t stream) {
    const float* x   = (const float*)d_in[0];
    const int*   idx = (const int*)d_in[1];
    float* out = (float*)d_out;
    int* wsmax = (int*)d_ws;

    // zero the atomic-max cell (d_ws is re-poisoned 0xAA each replay);
    // memset nodes are graph-capturable (the harness itself uses hipMemsetAsync).
    hipMemsetAsync(wsmax, 0, sizeof(int), stream);

    dim3 grid(NCHUNK, B_ / 2);
    clause_main<<<grid, NTH, 0, stream>>>(x, idx, out, wsmax);

    const int n4 = (B_ * G_) / 4;             // 160,000
    norm_out<<<(n4 + 255) / 256, 256, 0, stream>>>(out, wsmax, n4);
}

// Round 5
// 79.182 us; speedup vs baseline: 1.1468x; 1.1265x over previous
//
#include <hip/hip_runtime.h>
#include <hip/hip_fp16.h>

#define G_   5000
#define B_   128
#define S_   32
#define NTH  320      // 5 waves
#define GPB  313      // ceil(5000/16) g's per block
#define NCHUNK 16     // 16 chunks * 32 b-quads = 512 blocks = exactly 2/CU

union H2F { __half2 h2; float f; };
__device__ __forceinline__ float h2_as_f(__half2 h) { H2F u; u.h2 = h; return u.f; }
__device__ __forceinline__ __half2 f_as_h2(float f) { H2F u; u.f = f; return u.h2; }

// ---------------- main clause evaluation ---------------------------------------
// Block: 320 threads; owns 4 consecutive batch rows (blockIdx.y) and a chunk of
// 313 g's (blockIdx.x). x rows quantized to fp16 and staged 4-batch-interleaved
// in LDS (40,000 B): xi[4*i+j] = (half)x[b0+j][i]. One ds_read_b64 serves 4
// batches per gathered index; products via v_pk_mul_f16.
// fp16 error budget: body rel err <= ~7*2^-11 = 3.4e-3; logsumexp output is a
// convex combination of body perturbations => |d out| <= 3.4e-3; thr 1.94e-2.
__global__ __launch_bounds__(NTH)
void clause_main(const float* __restrict__ x,
                 const int*  __restrict__ idx,   // harness delivers int64 ref idx as int32
                 float* __restrict__ out,
                 int*   __restrict__ wsmax) {
    __shared__ __half xi[G_ * 4];         // 40,000 B
    __shared__ float red[NTH / 64];

    const int tid = threadIdx.x;
    const int b0  = blockIdx.y * 4;

    // ---- stage 4 x-rows -> fp16, interleaved; one ds_write_b128 per 2 columns ----
    const float2* r0 = (const float2*)(x + (size_t)(b0 + 0) * G_);
    const float2* r1 = (const float2*)(x + (size_t)(b0 + 1) * G_);
    const float2* r2 = (const float2*)(x + (size_t)(b0 + 2) * G_);
    const float2* r3 = (const float2*)(x + (size_t)(b0 + 3) * G_);
    float4* xi4 = (float4*)xi;
    for (int i = tid; i < G_ / 2; i += NTH) {
        float2 a0 = r0[i], a1 = r1[i], a2 = r2[i], a3 = r3[i];
        float4 w;
        w.x = h2_as_f(__floats2half2_rn(a0.x, a1.x));   // col 2i,   batches 0,1
        w.y = h2_as_f(__floats2half2_rn(a2.x, a3.x));   // col 2i,   batches 2,3
        w.z = h2_as_f(__floats2half2_rn(a0.y, a1.y));   // col 2i+1, batches 0,1
        w.w = h2_as_f(__floats2half2_rn(a2.y, a3.y));   // col 2i+1, batches 2,3
        xi4[i] = w;
    }
    __syncthreads();

    const int g = blockIdx.x * GPB + tid;
    const bool active = (tid < GPB) && (g < G_);
    const float2* xi2 = (const float2*)xi;   // one float2 = 4 halves = 4 batches of col i
    float m = 0.0f;

    if (active) {
        // gamma*lse(body/gamma) = 0.15 + 0.01*ln(sum_s exp(100*body_s - 15))
        // body in (0,1): term <= e^85, 32*e^85 ~ 2.6e38 < FLT_MAX; term >= e^-15.
        float acc0 = 0.0f, acc1 = 0.0f, acc2 = 0.0f, acc3 = 0.0f;
        const int4* ip = ((const int4*)idx) + (size_t)g * S_;
        #pragma unroll 4
        for (int s = 0; s < S_; ++s) {
            int4 id = ip[s];
            float2 w0 = xi2[id.x];
            float2 w1 = xi2[id.y];
            float2 w2 = xi2[id.z];
            float2 w3 = xi2[id.w];
            __half2 lo = __hmul2(__hmul2(f_as_h2(w0.x), f_as_h2(w1.x)),
                                 __hmul2(f_as_h2(w2.x), f_as_h2(w3.x)));
            __half2 hi = __hmul2(__hmul2(f_as_h2(w0.y), f_as_h2(w1.y)),
                                 __hmul2(f_as_h2(w2.y), f_as_h2(w3.y)));
            float2 b01 = __half22float2(lo);
            float2 b23 = __half22float2(hi);
            acc0 += __expf(fmaf(b01.x, 100.0f, -15.0f));
            acc1 += __expf(fmaf(b01.y, 100.0f, -15.0f));
            acc2 += __expf(fmaf(b23.x, 100.0f, -15.0f));
            acc3 += __expf(fmaf(b23.y, 100.0f, -15.0f));
        }
        float o0 = fmaf(0.01f, __logf(acc0), 0.15f);
        float o1 = fmaf(0.01f, __logf(acc1), 0.15f);
        float o2 = fmaf(0.01f, __logf(acc2), 0.15f);
        float o3 = fmaf(0.01f, __logf(acc3), 0.15f);
        out[(size_t)(b0 + 0) * G_ + g] = o0;
        out[(size_t)(b0 + 1) * G_ + g] = o1;
        out[(size_t)(b0 + 2) * G_ + g] = o2;
        out[(size_t)(b0 + 3) * G_ + g] = o3;
        m = fmaxf(fmaxf(o0, o1), fmaxf(o2, o3));
    }

    // ---- block max -> global atomic (positive floats: int-bit max == float max) ----
    #pragma unroll
    for (int off = 32; off >= 1; off >>= 1)
        m = fmaxf(m, __shfl_down(m, off));
    if ((tid & 63) == 0) red[tid >> 6] = m;
    __syncthreads();
    if (tid == 0) {
        float mm = red[0];
        #pragma unroll
        for (int w = 1; w < NTH / 64; ++w) mm = fmaxf(mm, red[w]);
        atomicMax(wsmax, __float_as_int(mm));
    }
}

// ---------------- conditional global-max normalization --------------------------
__global__ void norm_out(float* __restrict__ out, const int* __restrict__ wsmax, int n4) {
    int i = blockIdx.x * blockDim.x + threadIdx.x;
    float mv = __int_as_float(*wsmax);
    float s  = (mv > 1.0f) ? (1.0f / mv) : 1.0f;
    if (i < n4) {
        float4 v = ((float4*)out)[i];
        v.x *= s; v.y *= s; v.z *= s; v.w *= s;
        ((float4*)out)[i] = v;
    }
}

// ---------------- launcher ------------------------------------------------------
extern "C" void kernel_launch(void* const* d_in, const int* in_sizes, int n_in,
                              void* d_out, int out_size, void* d_ws, size_t ws_size,
                              hipStream_t stream) {
    const float* x   = (const float*)d_in[0];
    const int*   idx = (const int*)d_in[1];
    float* out = (float*)d_out;
    int* wsmax = (int*)d_ws;

    // zero the atomic-max cell (d_ws is re-poisoned 0xAA each replay)
    hipMemsetAsync(wsmax, 0, sizeof(int), stream);

    dim3 grid(NCHUNK, B_ / 4);
    clause_main<<<grid, NTH, 0, stream>>>(x, idx, out, wsmax);

    const int n4 = (B_ * G_) / 4;             // 160,000
    norm_out<<<(n4 + 255) / 256, 256, 0, stream>>>(out, wsmax, n4);
}